// Round 1
// baseline (1436.123 us; speedup 1.0000x reference)
//
#include <hip/hip_runtime.h>
#include <hip/hip_bf16.h>

typedef __attribute__((ext_vector_type(8))) __bf16 bf16x8;
typedef __attribute__((ext_vector_type(4))) __bf16 bf16x4;
typedef __attribute__((ext_vector_type(4))) float f32x4;

#define MFMA16(a, b, c) __builtin_amdgcn_mfma_f32_16x16x32_bf16((a), (b), (c), 0, 0, 0)

// ---------------------------------------------------------------------------
// fp32 -> bf16 elementwise convert, 4 elems/thread (float4 in, 8B out)
// ---------------------------------------------------------------------------
__global__ __launch_bounds__(256) void k_conv(const float* __restrict__ src,
                                              __bf16* __restrict__ dst, long n4) {
  long i = (long)blockIdx.x * 256 + threadIdx.x;
  if (i >= n4) return;
  float4 v = ((const float4*)src)[i];
  bf16x4 o;
  o[0] = (__bf16)v.x; o[1] = (__bf16)v.y; o[2] = (__bf16)v.z; o[3] = (__bf16)v.w;
  ((bf16x4*)dst)[i] = o;
}

// ---------------------------------------------------------------------------
// fp32 [R][C] -> bf16 [C][R] transpose-convert, 64x64 tiles via LDS
// ---------------------------------------------------------------------------
__global__ __launch_bounds__(256) void k_transpose_f32_bf16(
    const float* __restrict__ src, __bf16* __restrict__ dst, int R, int C) {
  __shared__ float tl[64][68];  // +4 pad breaks bank conflicts on column reads
  int tid = threadIdx.x;
  int r0 = blockIdx.y * 64, c0 = blockIdx.x * 64;
#pragma unroll
  for (int j = 0; j < 4; ++j) {
    int idx = j * 256 + tid;
    int row = idx >> 4, q4 = (idx & 15) * 4;
    float4 v = *(const float4*)(src + (size_t)(r0 + row) * C + c0 + q4);
    tl[row][q4 + 0] = v.x; tl[row][q4 + 1] = v.y;
    tl[row][q4 + 2] = v.z; tl[row][q4 + 3] = v.w;
  }
  __syncthreads();
#pragma unroll
  for (int j = 0; j < 2; ++j) {
    int idx = j * 256 + tid;
    int orow = idx >> 3, ch = (idx & 7) * 8;
    bf16x8 pk;
#pragma unroll
    for (int e = 0; e < 8; ++e) pk[e] = (__bf16)tl[ch + e][orow];
    *(bf16x8*)(dst + (size_t)(c0 + orow) * R + r0 + ch) = pk;
  }
}

// ---------------------------------------------------------------------------
// V slice of qkv -> Vt[pair][d][s]  (bf16 transpose per (b,h) pair)
// qkv: [4096 tokens][12288], V part at col 8192 + h*512
// ---------------------------------------------------------------------------
__global__ __launch_bounds__(256) void k_transpose_v(
    const __bf16* __restrict__ qkv, __bf16* __restrict__ vt) {
  __shared__ __bf16 tl[64][72];
  int tid = threadIdx.x;
  int p = blockIdx.z, b = p >> 3, h = p & 7;
  int d0 = blockIdx.x * 64, s0 = blockIdx.y * 64;
  const __bf16* src = qkv + (size_t)b * 1024 * 12288 + 8192 + h * 512;
#pragma unroll
  for (int j = 0; j < 2; ++j) {
    int idx = j * 256 + tid;
    int row = idx >> 3, ch = (idx & 7) * 8;
    bf16x8 v = *(const bf16x8*)(src + (size_t)(s0 + row) * 12288 + d0 + ch);
#pragma unroll
    for (int e = 0; e < 8; ++e) tl[row][ch + e] = v[e];
  }
  __syncthreads();
#pragma unroll
  for (int j = 0; j < 2; ++j) {
    int idx = j * 256 + tid;
    int orow = idx >> 3, ch = (idx & 7) * 8;
    bf16x8 pk;
#pragma unroll
    for (int e = 0; e < 8; ++e) pk[e] = tl[ch + e][orow];
    *(bf16x8*)(vt + (size_t)p * 524288 + (size_t)(d0 + orow) * 1024 + s0 + ch) = pk;
  }
}

// ---------------------------------------------------------------------------
// GEMM: C[M][N] = A[M][K] * Bt[N][K]^T   (both bf16, fp32 accum)
// 128x128 tile, BK=64, 4 waves (2x2), each wave 64x64 = 4x4 16x16x32 frags.
// global_load_lds(16B) staging with XOR-chunk swizzle applied on the SOURCE
// address (linear LDS dest) and on the ds_read side -> ~2-way conflicts only.
// ---------------------------------------------------------------------------
__device__ __forceinline__ void stage_tile(const __bf16* __restrict__ g, int ld,
                                           __bf16* lds) {
  int tid = threadIdx.x;
  int w = tid >> 6, lane = tid & 63;
#pragma unroll
  for (int i = 0; i < 4; ++i) {
    int c = w * 256 + i * 64 + lane;        // 16B-chunk id, 1024 chunks = 16KB
    int row = c >> 3, slot = c & 7;         // 8 chunks (128B) per row
    const __bf16* src = g + (size_t)row * ld + ((slot ^ (row & 7)) << 3);
    __bf16* dst = lds + (size_t)(w * 256 + i * 64) * 8;  // wave-uniform base
    __builtin_amdgcn_global_load_lds(
        (const __attribute__((address_space(1))) void*)src,
        (__attribute__((address_space(3))) void*)dst, 16, 0, 0);
  }
}

template <int OUTF32>
__global__ __launch_bounds__(256) void k_gemm_bt(
    const __bf16* __restrict__ A, const __bf16* __restrict__ Bt,
    void* __restrict__ Cout, const float* __restrict__ bias,
    int M, int N, int K) {
  __shared__ __align__(16) __bf16 As[128 * 64];
  __shared__ __align__(16) __bf16 Bs[128 * 64];
  int tid = threadIdx.x, lane = tid & 63, w = tid >> 6;
  int r16 = lane & 15, g = lane >> 4;
  int m0 = blockIdx.y * 128, n0 = blockIdx.x * 128;
  int wr = (w >> 1) * 64, wc = (w & 1) * 64;
  f32x4 acc[4][4];
#pragma unroll
  for (int a = 0; a < 4; ++a)
#pragma unroll
    for (int bq = 0; bq < 4; ++bq) acc[a][bq] = f32x4{0.f, 0.f, 0.f, 0.f};

  const __bf16* Ag = A + (size_t)m0 * K;
  const __bf16* Bg = Bt + (size_t)n0 * K;
  for (int kt = 0; kt < K; kt += 64) {
    __syncthreads();              // everyone done reading previous tile
    stage_tile(Ag + kt, K, As);
    stage_tile(Bg + kt, K, Bs);
    __syncthreads();              // compiler drains vmcnt before barrier
#pragma unroll
    for (int ks = 0; ks < 2; ++ks) {
      bf16x8 af[4], bfr[4];
#pragma unroll
      for (int mi = 0; mi < 4; ++mi) {
        int r = wr + mi * 16 + r16;
        int gg = ks * 4 + g;
        af[mi] = *(const bf16x8*)((const char*)As + r * 128 + ((gg ^ (r & 7)) << 4));
      }
#pragma unroll
      for (int ni = 0; ni < 4; ++ni) {
        int r = wc + ni * 16 + r16;
        int gg = ks * 4 + g;
        bfr[ni] = *(const bf16x8*)((const char*)Bs + r * 128 + ((gg ^ (r & 7)) << 4));
      }
#pragma unroll
      for (int mi = 0; mi < 4; ++mi)
#pragma unroll
        for (int ni = 0; ni < 4; ++ni)
          acc[mi][ni] = MFMA16(af[mi], bfr[ni], acc[mi][ni]);
    }
  }
  // epilogue: C/D layout row=(lane>>4)*4+i, col=lane&15  [measured m89]
#pragma unroll
  for (int mi = 0; mi < 4; ++mi) {
#pragma unroll
    for (int ni = 0; ni < 4; ++ni) {
#pragma unroll
      for (int i = 0; i < 4; ++i) {
        int row = m0 + wr + mi * 16 + g * 4 + i;
        int col = n0 + wc + ni * 16 + r16;
        float v = acc[mi][ni][i];
        if (OUTF32) {
          ((float*)Cout)[(size_t)row * N + col] = v + bias[col];
        } else {
          ((__bf16*)Cout)[(size_t)row * N + col] = (__bf16)v;
        }
      }
    }
  }
}

// ---------------------------------------------------------------------------
// Attention. One block = (pair p=b*8+h, 64 q-rows); 4 waves x 16 q-rows.
// Scores are tiny (std~0.35) -> softmax WITHOUT max subtraction is fp32-safe:
// O = (sum_s e^{s} v_s) / (sum_s e^{s}).  Row-sum l via MFMA against ones-B,
// so the final divide is lane-local (same C layout as O). Zero cross-lane ops.
// K and Vt fragments read directly from global (1MB/head, L2-resident).
// P (C layout) -> per-wave padded LDS -> A-fragment (16B ds_read_b128).
// ---------------------------------------------------------------------------
__global__ __launch_bounds__(256) void k_attn(
    const __bf16* __restrict__ qkv, const __bf16* __restrict__ vt,
    __bf16* __restrict__ o) {
  const float scale = 1.0f / 64.0f;  // embed_dim^-0.5 = 4096^-0.5
  int qb = blockIdx.x, p = blockIdx.y;
  int b = p >> 3, h = p & 7;
  int tid = threadIdx.x, w = tid >> 6, lane = tid & 63;
  int r16 = lane & 15, g = lane >> 4;
  int qbase = b * 1024 + qb * 64 + w * 16;
  const __bf16* Q = qkv + (size_t)(qbase + r16) * 12288 + h * 512;
  const __bf16* Kp = qkv + (size_t)b * 1024 * 12288 + 4096 + h * 512;
  const __bf16* V = vt + (size_t)p * 524288;  // [512 d][1024 s]
  __shared__ __align__(16) __bf16 plds[4][16][40];  // per-wave P tile, 80B rows

  // Hoist Q fragments: 16 frags x 8 bf16 = 64 VGPRs
  bf16x8 qf[16];
#pragma unroll
  for (int kk = 0; kk < 16; ++kk)
    qf[kk] = *(const bf16x8*)(Q + kk * 32 + g * 8);

  f32x4 accO[32];
#pragma unroll
  for (int dt = 0; dt < 32; ++dt) accO[dt] = f32x4{0.f, 0.f, 0.f, 0.f};
  f32x4 accL = f32x4{0.f, 0.f, 0.f, 0.f};
  bf16x8 ones;
#pragma unroll
  for (int e = 0; e < 8; ++e) ones[e] = (__bf16)1.0f;

  for (int st = 0; st < 32; ++st) {
    int s0 = st * 32;
    f32x4 sA = f32x4{0.f, 0.f, 0.f, 0.f};
    f32x4 sB = f32x4{0.f, 0.f, 0.f, 0.f};
#pragma unroll
    for (int kk = 0; kk < 16; ++kk) {
      bf16x8 kf0 = *(const bf16x8*)(Kp + (size_t)(s0 + r16) * 12288 + kk * 32 + g * 8);
      bf16x8 kf1 = *(const bf16x8*)(Kp + (size_t)(s0 + 16 + r16) * 12288 + kk * 32 + g * 8);
      sA = MFMA16(qf[kk], kf0, sA);
      sB = MFMA16(qf[kk], kf1, sB);
    }
    // exp (fp32), store P tile in C layout to LDS
#pragma unroll
    for (int i = 0; i < 4; ++i) {
      plds[w][g * 4 + i][r16] = (__bf16)__expf(sA[i] * scale);
      plds[w][g * 4 + i][16 + r16] = (__bf16)__expf(sB[i] * scale);
    }
    // re-read as A-fragment (same wave; compiler inserts lgkmcnt wait)
    bf16x8 pa = *(const bf16x8*)(&plds[w][r16][g * 8]);
    accL = MFMA16(pa, ones, accL);  // row sums (broadcast across cols)
#pragma unroll
    for (int dt = 0; dt < 32; ++dt) {
      bf16x8 bv = *(const bf16x8*)(V + (size_t)(dt * 16 + r16) * 1024 + s0 + g * 8);
      accO[dt] = MFMA16(pa, bv, accO[dt]);
    }
  }
#pragma unroll
  for (int dt = 0; dt < 32; ++dt) {
#pragma unroll
    for (int i = 0; i < 4; ++i) {
      float ov = accO[dt][i] / accL[i];
      o[(size_t)(qbase + g * 4 + i) * 4096 + h * 512 + dt * 16 + r16] = (__bf16)ov;
    }
  }
}

// ---------------------------------------------------------------------------
// Orchestration.
// ws layout (256 MB total):
//   [0,   33.5MB) xb   (x in bf16)            -> reused as attnO after GEMM1
//   [33.5,134.2 ) wT   (WqkvT bf16 [12288][4096]) -> reused as WoutT
//   [134.2,234.9) qkv  (bf16 [4096][12288])
//   [234.9,268.4) vt   (bf16 [32][512][1024])
// ---------------------------------------------------------------------------
extern "C" void kernel_launch(void* const* d_in, const int* in_sizes, int n_in,
                              void* d_out, int out_size, void* d_ws, size_t ws_size,
                              hipStream_t stream) {
  const float* x = (const float*)d_in[0];
  const float* Wqkv = (const float*)d_in[1];
  const float* Wout = (const float*)d_in[2];
  const float* bout = (const float*)d_in[3];
  float* out = (float*)d_out;
  char* ws = (char*)d_ws;

  __bf16* xb = (__bf16*)(ws);                   // 33,554,432 B
  __bf16* wT = (__bf16*)(ws + 33554432);        // 100,663,296 B
  __bf16* qkv = (__bf16*)(ws + 134217728);      // 100,663,296 B
  __bf16* vt = (__bf16*)(ws + 234881024);       // 33,554,432 B

  // 1. x -> bf16 (16.8M elems, 4/thread)
  k_conv<<<16384, 256, 0, stream>>>(x, xb, 4194304);
  // 2. WqkvT = transpose(Wqkv) in bf16: [4096][12288] -> [12288][4096]
  k_transpose_f32_bf16<<<dim3(192, 64), 256, 0, stream>>>(Wqkv, wT, 4096, 12288);
  // 3. qkv = xb @ Wqkv  (bf16 out)
  k_gemm_bt<0><<<dim3(96, 32), 256, 0, stream>>>(xb, wT, qkv, nullptr, 4096, 12288, 4096);
  // 4. vt = per-pair transpose of V
  k_transpose_v<<<dim3(8, 16, 32), 256, 0, stream>>>(qkv, vt);
  // 5. attention -> attnO (reuses xb region)
  k_attn<<<dim3(16, 32), 256, 0, stream>>>(qkv, vt, xb);
  // 6. WoutT (reuses wT region; GEMM1 already consumed WqkvT)
  k_transpose_f32_bf16<<<dim3(64, 64), 256, 0, stream>>>(Wout, wT, 4096, 4096);
  // 7. out = attnO @ Wout + bout  (fp32 out, fused bias)
  k_gemm_bt<1><<<dim3(32, 32), 256, 0, stream>>>(xb, wT, out, bout, 4096, 4096, 4096);
}

// Round 2
// 829.382 us; speedup vs baseline: 1.7316x; 1.7316x over previous
//
#include <hip/hip_runtime.h>
#include <hip/hip_bf16.h>

typedef __attribute__((ext_vector_type(8))) __bf16 bf16x8;
typedef __attribute__((ext_vector_type(4))) __bf16 bf16x4;
typedef __attribute__((ext_vector_type(4))) float f32x4;

#define MFMA16(a, b, c) __builtin_amdgcn_mfma_f32_16x16x32_bf16((a), (b), (c), 0, 0, 0)

// ---------------------------------------------------------------------------
// fp32 -> bf16 elementwise convert, 4 elems/thread (float4 in, 8B out)
// ---------------------------------------------------------------------------
__global__ __launch_bounds__(256) void k_conv(const float* __restrict__ src,
                                              __bf16* __restrict__ dst, long n4) {
  long i = (long)blockIdx.x * 256 + threadIdx.x;
  if (i >= n4) return;
  float4 v = ((const float4*)src)[i];
  bf16x4 o;
  o[0] = (__bf16)v.x; o[1] = (__bf16)v.y; o[2] = (__bf16)v.z; o[3] = (__bf16)v.w;
  ((bf16x4*)dst)[i] = o;
}

// ---------------------------------------------------------------------------
// fp32 [R][C] -> bf16 [C][R] transpose-convert, 64x64 tiles via LDS
// ---------------------------------------------------------------------------
__global__ __launch_bounds__(256) void k_transpose_f32_bf16(
    const float* __restrict__ src, __bf16* __restrict__ dst, int R, int C) {
  __shared__ float tl[64][68];
  int tid = threadIdx.x;
  int r0 = blockIdx.y * 64, c0 = blockIdx.x * 64;
#pragma unroll
  for (int j = 0; j < 4; ++j) {
    int idx = j * 256 + tid;
    int row = idx >> 4, q4 = (idx & 15) * 4;
    float4 v = *(const float4*)(src + (size_t)(r0 + row) * C + c0 + q4);
    tl[row][q4 + 0] = v.x; tl[row][q4 + 1] = v.y;
    tl[row][q4 + 2] = v.z; tl[row][q4 + 3] = v.w;
  }
  __syncthreads();
#pragma unroll
  for (int j = 0; j < 2; ++j) {
    int idx = j * 256 + tid;
    int orow = idx >> 3, ch = (idx & 7) * 8;
    bf16x8 pk;
#pragma unroll
    for (int e = 0; e < 8; ++e) pk[e] = (__bf16)tl[ch + e][orow];
    *(bf16x8*)(dst + (size_t)(c0 + orow) * R + r0 + ch) = pk;
  }
}

// ---------------------------------------------------------------------------
// V slice of qkv -> Vt[pair][d][s]  (bf16 transpose per (b,h) pair)
// ---------------------------------------------------------------------------
__global__ __launch_bounds__(256) void k_transpose_v(
    const __bf16* __restrict__ qkv, __bf16* __restrict__ vt) {
  __shared__ __bf16 tl[64][72];
  int tid = threadIdx.x;
  int p = blockIdx.z, b = p >> 3, h = p & 7;
  int d0 = blockIdx.x * 64, s0 = blockIdx.y * 64;
  const __bf16* src = qkv + (size_t)b * 1024 * 12288 + 8192 + h * 512;
#pragma unroll
  for (int j = 0; j < 2; ++j) {
    int idx = j * 256 + tid;
    int row = idx >> 3, ch = (idx & 7) * 8;
    bf16x8 v = *(const bf16x8*)(src + (size_t)(s0 + row) * 12288 + d0 + ch);
#pragma unroll
    for (int e = 0; e < 8; ++e) tl[row][ch + e] = v[e];
  }
  __syncthreads();
#pragma unroll
  for (int j = 0; j < 2; ++j) {
    int idx = j * 256 + tid;
    int orow = idx >> 3, ch = (idx & 7) * 8;
    bf16x8 pk;
#pragma unroll
    for (int e = 0; e < 8; ++e) pk[e] = tl[ch + e][orow];
    *(bf16x8*)(vt + (size_t)p * 524288 + (size_t)(d0 + orow) * 1024 + s0 + ch) = pk;
  }
}

// ---------------------------------------------------------------------------
// Shared GEMM machinery: 128x128 tile, BK=64, 4 waves (2x2), 4x4 frags/wave.
// global_load_lds(16B), XOR-chunk swizzle on SOURCE addr (linear LDS dest).
// ---------------------------------------------------------------------------
__device__ __forceinline__ void stage_tile(const __bf16* __restrict__ g, int ld,
                                           __bf16* lds) {
  int tid = threadIdx.x;
  int w = tid >> 6, lane = tid & 63;
#pragma unroll
  for (int i = 0; i < 4; ++i) {
    int c = w * 256 + i * 64 + lane;
    int row = c >> 3, slot = c & 7;
    const __bf16* src = g + (size_t)row * ld + ((slot ^ (row & 7)) << 3);
    __bf16* dst = lds + (size_t)(w * 256 + i * 64) * 8;
    __builtin_amdgcn_global_load_lds(
        (const __attribute__((address_space(1))) void*)src,
        (__attribute__((address_space(3))) void*)dst, 16, 0, 0);
  }
}

struct FragIdx {
  int lane, w, r16, g, wr, wc;
};
__device__ __forceinline__ FragIdx frag_idx() {
  FragIdx f;
  int tid = threadIdx.x;
  f.lane = tid & 63; f.w = tid >> 6;
  f.r16 = f.lane & 15; f.g = f.lane >> 4;
  f.wr = (f.w >> 1) * 64; f.wc = (f.w & 1) * 64;
  return f;
}

// main-loop body shared by all GEMMs (K multiple of 64)
#define GEMM_MAIN_LOOP(A_, lda_, B_, ldb_, K_, As_, Bs_, acc_, F_)            \
  for (int kt = 0; kt < (K_); kt += 64) {                                     \
    __syncthreads();                                                          \
    stage_tile((A_) + kt, (lda_), As_);                                       \
    stage_tile((B_) + kt, (ldb_), Bs_);                                       \
    __syncthreads();                                                          \
    _Pragma("unroll") for (int ks = 0; ks < 2; ++ks) {                        \
      bf16x8 af[4], bfr[4];                                                   \
      _Pragma("unroll") for (int mi = 0; mi < 4; ++mi) {                      \
        int r = F_.wr + mi * 16 + F_.r16;                                     \
        int gg = ks * 4 + F_.g;                                               \
        af[mi] = *(const bf16x8*)((const char*)As_ + r * 128 +                \
                                  ((gg ^ (r & 7)) << 4));                     \
      }                                                                       \
      _Pragma("unroll") for (int ni = 0; ni < 4; ++ni) {                      \
        int r = F_.wc + ni * 16 + F_.r16;                                     \
        int gg = ks * 4 + F_.g;                                               \
        bfr[ni] = *(const bf16x8*)((const char*)Bs_ + r * 128 +               \
                                   ((gg ^ (r & 7)) << 4));                    \
      }                                                                       \
      _Pragma("unroll") for (int mi = 0; mi < 4; ++mi)                        \
          _Pragma("unroll") for (int ni = 0; ni < 4; ++ni)                    \
              acc_[mi][ni] = MFMA16(af[mi], bfr[ni], acc_[mi][ni]);           \
    }                                                                         \
  }

// ---------------------------------------------------------------------------
// Plain GEMM: C[M][N] = A[M][K] * Bt[N][K]^T
// ---------------------------------------------------------------------------
template <int OUTF32>
__global__ __launch_bounds__(256) void k_gemm_bt(
    const __bf16* __restrict__ A, const __bf16* __restrict__ Bt,
    void* __restrict__ Cout, const float* __restrict__ bias,
    int M, int N, int K) {
  __shared__ __align__(16) __bf16 As[128 * 64];
  __shared__ __align__(16) __bf16 Bs[128 * 64];
  FragIdx F = frag_idx();
  int m0 = blockIdx.y * 128, n0 = blockIdx.x * 128;
  f32x4 acc[4][4];
#pragma unroll
  for (int a = 0; a < 4; ++a)
#pragma unroll
    for (int bq = 0; bq < 4; ++bq) acc[a][bq] = f32x4{0.f, 0.f, 0.f, 0.f};

  const __bf16* Ag = A + (size_t)m0 * K;
  const __bf16* Bg = Bt + (size_t)n0 * K;
  GEMM_MAIN_LOOP(Ag, K, Bg, K, K, As, Bs, acc, F)
#pragma unroll
  for (int mi = 0; mi < 4; ++mi) {
#pragma unroll
    for (int ni = 0; ni < 4; ++ni) {
#pragma unroll
      for (int i = 0; i < 4; ++i) {
        int row = m0 + F.wr + mi * 16 + F.g * 4 + i;
        int col = n0 + F.wc + ni * 16 + F.r16;
        float v = acc[mi][ni][i];
        if (OUTF32) {
          ((float*)Cout)[(size_t)row * N + col] = v + bias[col];
        } else {
          ((__bf16*)Cout)[(size_t)row * N + col] = (__bf16)v;
        }
      }
    }
  }
}

// ---------------------------------------------------------------------------
// Batched attention GEMMs (one (b,h) pair per blockIdx.z):
// PHASE 0: P[z][t][s] = exp(scale * (Q_z K_z^T)[t][s])     M=N=1024, K=512
// PHASE 1: O[b*1024+t][h*512+d] = (P_z Vt_z^T)[t][d]/L[z][t]  M=1024,N=512,K=1024
// ---------------------------------------------------------------------------
template <int PHASE>
__global__ __launch_bounds__(256) void k_attn_gemm(
    const __bf16* __restrict__ qkv, const __bf16* __restrict__ vt,
    const __bf16* __restrict__ P, const float* __restrict__ L,
    __bf16* __restrict__ outP, __bf16* __restrict__ outO) {
  __shared__ __align__(16) __bf16 As[128 * 64];
  __shared__ __align__(16) __bf16 Bs[128 * 64];
  const float scale = 1.0f / 64.0f;  // 4096^-0.5
  FragIdx F = frag_idx();
  int z = blockIdx.z, b = z >> 3, h = z & 7;
  int m0 = blockIdx.y * 128, n0 = blockIdx.x * 128;

  const __bf16* A;
  const __bf16* Bt;
  int lda, ldb, K;
  if (PHASE == 0) {
    A = qkv + (size_t)b * 1024 * 12288 + h * 512;          lda = 12288;
    Bt = qkv + (size_t)b * 1024 * 12288 + 4096 + h * 512;  ldb = 12288;
    K = 512;
  } else {
    A = P + (size_t)z * 1048576;   lda = 1024;
    Bt = vt + (size_t)z * 524288;  ldb = 1024;
    K = 1024;
  }

  f32x4 acc[4][4];
#pragma unroll
  for (int a = 0; a < 4; ++a)
#pragma unroll
    for (int bq = 0; bq < 4; ++bq) acc[a][bq] = f32x4{0.f, 0.f, 0.f, 0.f};

  const __bf16* Ag = A + (size_t)m0 * lda;
  const __bf16* Bg = Bt + (size_t)n0 * ldb;
  GEMM_MAIN_LOOP(Ag, lda, Bg, ldb, K, As, Bs, acc, F)

#pragma unroll
  for (int mi = 0; mi < 4; ++mi) {
#pragma unroll
    for (int ni = 0; ni < 4; ++ni) {
#pragma unroll
      for (int i = 0; i < 4; ++i) {
        int row = m0 + F.wr + mi * 16 + F.g * 4 + i;
        int col = n0 + F.wc + ni * 16 + F.r16;
        if (PHASE == 0) {
          outP[(size_t)z * 1048576 + (size_t)row * 1024 + col] =
              (__bf16)__expf(acc[mi][ni][i] * scale);
        } else {
          float l = L[z * 1024 + row];
          outO[(size_t)(b * 1024 + row) * 4096 + h * 512 + col] =
              (__bf16)(acc[mi][ni][i] / l);
        }
      }
    }
  }
}

// ---------------------------------------------------------------------------
// Row sums of P: L[p*1024+t] = sum_s P[p][t][s].  One wave per row.
// ---------------------------------------------------------------------------
__global__ __launch_bounds__(256) void k_lsum(const __bf16* __restrict__ P,
                                              float* __restrict__ L) {
  int row = blockIdx.x * 4 + (threadIdx.x >> 6);
  int lane = threadIdx.x & 63;
  const __bf16* pr = P + (size_t)row * 1024;
  float s = 0.f;
#pragma unroll
  for (int j = 0; j < 2; ++j) {
    bf16x8 v = *(const bf16x8*)(pr + (j * 64 + lane) * 8);
#pragma unroll
    for (int e = 0; e < 8; ++e) s += (float)v[e];
  }
#pragma unroll
  for (int off = 32; off; off >>= 1) s += __shfl_down(s, off, 64);
  if (lane == 0) L[row] = s;
}

// ---------------------------------------------------------------------------
// Orchestration. ws layout (256 MiB):
//   [0,        33.5MB)  xb   (x bf16)         -> reused as attnO
//   [33.5MB,  134.2MB)  wT   (WqkvT bf16)     -> reused as P(64MB)+L, then WoutT
//   [134.2MB, 234.9MB)  qkv
//   [234.9MB, 268.4MB)  vt
// ---------------------------------------------------------------------------
extern "C" void kernel_launch(void* const* d_in, const int* in_sizes, int n_in,
                              void* d_out, int out_size, void* d_ws, size_t ws_size,
                              hipStream_t stream) {
  const float* x = (const float*)d_in[0];
  const float* Wqkv = (const float*)d_in[1];
  const float* Wout = (const float*)d_in[2];
  const float* bout = (const float*)d_in[3];
  float* out = (float*)d_out;
  char* ws = (char*)d_ws;

  __bf16* xb = (__bf16*)(ws);
  __bf16* wT = (__bf16*)(ws + 33554432);
  __bf16* P = (__bf16*)(ws + 33554432);            // aliases wT (free after GEMM1)
  float* L = (float*)(ws + 33554432 + 67108864);   // 128KB, still inside wT region
  __bf16* qkv = (__bf16*)(ws + 134217728);
  __bf16* vt = (__bf16*)(ws + 234881024);

  // 1. x -> bf16
  k_conv<<<16384, 256, 0, stream>>>(x, xb, 4194304);
  // 2. WqkvT
  k_transpose_f32_bf16<<<dim3(192, 64), 256, 0, stream>>>(Wqkv, wT, 4096, 12288);
  // 3. qkv = xb @ Wqkv
  k_gemm_bt<0><<<dim3(96, 32), 256, 0, stream>>>(xb, wT, qkv, nullptr, 4096, 12288, 4096);
  // 4. vt = per-pair V transpose
  k_transpose_v<<<dim3(8, 16, 32), 256, 0, stream>>>(qkv, vt);
  // 5. P = exp(scale * Q K^T)   (overwrites WqkvT region)
  k_attn_gemm<0><<<dim3(8, 8, 32), 256, 0, stream>>>(qkv, vt, nullptr, nullptr, P, nullptr);
  // 6. L = row sums of P
  k_lsum<<<8192, 256, 0, stream>>>(P, L);
  // 7. attnO = (P @ V) / L  -> xb region
  k_attn_gemm<1><<<dim3(4, 8, 32), 256, 0, stream>>>(qkv, vt, P, L, nullptr, xb);
  // 8. WoutT (overwrites P region; P consumed)
  k_transpose_f32_bf16<<<dim3(64, 64), 256, 0, stream>>>(Wout, wT, 4096, 4096);
  // 9. out = attnO @ Wout + bout
  k_gemm_bt<1><<<dim3(32, 32), 256, 0, stream>>>(xb, wT, out, bout, 4096, 4096, 4096);
}

// Round 3
// 674.114 us; speedup vs baseline: 2.1304x; 1.2303x over previous
//
#include <hip/hip_runtime.h>
#include <hip/hip_bf16.h>

typedef __attribute__((ext_vector_type(8))) __bf16 bf16x8;
typedef __attribute__((ext_vector_type(4))) __bf16 bf16x4;
typedef __attribute__((ext_vector_type(4))) float f32x4;

#define MFMA16(a, b, c) __builtin_amdgcn_mfma_f32_16x16x32_bf16((a), (b), (c), 0, 0, 0)

// ---------------------------------------------------------------------------
// fp32 -> bf16 elementwise convert
// ---------------------------------------------------------------------------
__global__ __launch_bounds__(256) void k_conv(const float* __restrict__ src,
                                              __bf16* __restrict__ dst, long n4) {
  long i = (long)blockIdx.x * 256 + threadIdx.x;
  if (i >= n4) return;
  float4 v = ((const float4*)src)[i];
  bf16x4 o;
  o[0] = (__bf16)v.x; o[1] = (__bf16)v.y; o[2] = (__bf16)v.z; o[3] = (__bf16)v.w;
  ((bf16x4*)dst)[i] = o;
}

// ---------------------------------------------------------------------------
// fp32 [R][C] -> bf16 [C][R] transpose-convert
// ---------------------------------------------------------------------------
__global__ __launch_bounds__(256) void k_transpose_f32_bf16(
    const float* __restrict__ src, __bf16* __restrict__ dst, int R, int C) {
  __shared__ float tl[64][68];
  int tid = threadIdx.x;
  int r0 = blockIdx.y * 64, c0 = blockIdx.x * 64;
#pragma unroll
  for (int j = 0; j < 4; ++j) {
    int idx = j * 256 + tid;
    int row = idx >> 4, q4 = (idx & 15) * 4;
    float4 v = *(const float4*)(src + (size_t)(r0 + row) * C + c0 + q4);
    tl[row][q4 + 0] = v.x; tl[row][q4 + 1] = v.y;
    tl[row][q4 + 2] = v.z; tl[row][q4 + 3] = v.w;
  }
  __syncthreads();
#pragma unroll
  for (int j = 0; j < 2; ++j) {
    int idx = j * 256 + tid;
    int orow = idx >> 3, ch = (idx & 7) * 8;
    bf16x8 pk;
#pragma unroll
    for (int e = 0; e < 8; ++e) pk[e] = (__bf16)tl[ch + e][orow];
    *(bf16x8*)(dst + (size_t)(c0 + orow) * R + r0 + ch) = pk;
  }
}

// ---------------------------------------------------------------------------
// V slice of qkv -> Vt[pair][d][s]
// ---------------------------------------------------------------------------
__global__ __launch_bounds__(256) void k_transpose_v(
    const __bf16* __restrict__ qkv, __bf16* __restrict__ vt) {
  __shared__ __bf16 tl[64][72];
  int tid = threadIdx.x;
  int p = blockIdx.z, b = p >> 3, h = p & 7;
  int d0 = blockIdx.x * 64, s0 = blockIdx.y * 64;
  const __bf16* src = qkv + (size_t)b * 1024 * 12288 + 8192 + h * 512;
#pragma unroll
  for (int j = 0; j < 2; ++j) {
    int idx = j * 256 + tid;
    int row = idx >> 3, ch = (idx & 7) * 8;
    bf16x8 v = *(const bf16x8*)(src + (size_t)(s0 + row) * 12288 + d0 + ch);
#pragma unroll
    for (int e = 0; e < 8; ++e) tl[row][ch + e] = v[e];
  }
  __syncthreads();
#pragma unroll
  for (int j = 0; j < 2; ++j) {
    int idx = j * 256 + tid;
    int orow = idx >> 3, ch = (idx & 7) * 8;
    bf16x8 pk;
#pragma unroll
    for (int e = 0; e < 8; ++e) pk[e] = tl[ch + e][orow];
    *(bf16x8*)(vt + (size_t)p * 524288 + (size_t)(d0 + orow) * 1024 + s0 + ch) = pk;
  }
}

// ---------------------------------------------------------------------------
// 256x256 8-phase GEMM (HK-style schedule, plain HIP).
// C[M][N] = A[M][K] * Bt[N][K]^T, bf16 in, fp32 accum.
// 512 threads = 8 waves (2M x 4N); per-wave 128x64 output (acc[8][4] f32x4).
// BK=64. LDS 128KB: A[2buf][2half][128r][64c] + B same; half = interleaved
// row sets (A-half h: rows with bit6 of wave-local row == h; B: bit5).
// Per tile, half-tiles staged 4 phases ahead in order [Ah0,Bh1,Ah1,Bh0];
// vmcnt(6) only at phases 4/8 (14 outstanding -> waits next tile's 8 loads).
// MODE: 0 = bf16 out; 1 = fp32 out + bias; 2 = bf16 exp(acc/64) -> P;
//       3 = bf16 acc/L -> attnO scatter.
// ---------------------------------------------------------------------------
#define BARRIER() __builtin_amdgcn_s_barrier()
#define VMC6() asm volatile("s_waitcnt vmcnt(6)" ::: "memory")
#define WAITDS()                                     \
  do {                                               \
    asm volatile("s_waitcnt lgkmcnt(0)" ::: "memory"); \
    __builtin_amdgcn_sched_barrier(0);               \
  } while (0)

#define LDA(buf, mh)                                                          \
  do {                                                                        \
    _Pragma("unroll") for (int mi = 0; mi < 4; ++mi) {                        \
      int r = wm * 64 + mi * 16 + r16;                                        \
      _Pragma("unroll") for (int ks = 0; ks < 2; ++ks) {                      \
        int gg = ks * 4 + g;                                                  \
        af[mi][ks] = *(const bf16x8*)(ldsB + (buf)*32768 + (mh)*16384 +       \
                                      r * 128 + ((gg ^ (r & 7)) << 4));       \
      }                                                                       \
    }                                                                         \
  } while (0)

#define LDB(buf, nh, BQ)                                                      \
  do {                                                                        \
    _Pragma("unroll") for (int ni = 0; ni < 2; ++ni) {                        \
      int r = wn * 32 + ni * 16 + r16;                                        \
      _Pragma("unroll") for (int ks = 0; ks < 2; ++ks) {                      \
        int gg = ks * 4 + g;                                                  \
        BQ[ni][ks] = *(const bf16x8*)(ldsB + 65536 + (buf)*32768 +            \
                                      (nh)*16384 + r * 128 +                  \
                                      ((gg ^ (r & 7)) << 4));                 \
      }                                                                       \
    }                                                                         \
  } while (0)

#define QUAD(mh, nh, BQ)                                                      \
  do {                                                                        \
    __builtin_amdgcn_s_setprio(1);                                            \
    _Pragma("unroll") for (int ks = 0; ks < 2; ++ks)                          \
        _Pragma("unroll") for (int mi = 0; mi < 4; ++mi)                      \
            _Pragma("unroll") for (int ni = 0; ni < 2; ++ni)                  \
                acc[(mh)*4 + mi][(nh)*2 + ni] =                               \
                    MFMA16(af[mi][ks], BQ[ni][ks],                            \
                           acc[(mh)*4 + mi][(nh)*2 + ni]);                    \
    __builtin_amdgcn_s_setprio(0);                                            \
    __builtin_amdgcn_sched_barrier(0);                                        \
  } while (0)

#define STAGE_A(mh, tau)                                                      \
  do {                                                                        \
    int tc = (tau) < NT ? (tau) : NT - 1;                                     \
    char* dbase = ldsB + ((tau)&1) * 32768 + (mh)*16384;                      \
    _Pragma("unroll") for (int i = 0; i < 2; ++i)                             \
        __builtin_amdgcn_global_load_lds(                                     \
            (const __attribute__((address_space(1))) void*)(Ap +              \
                offA[i][mh] + tc * 64),                                       \
            (__attribute__((address_space(3))) void*)(dbase +                 \
                (i * 512 + w * 64) * 16), 16, 0, 0);                          \
  } while (0)

#define STAGE_B(nh, tau)                                                      \
  do {                                                                        \
    int tc = (tau) < NT ? (tau) : NT - 1;                                     \
    char* dbase = ldsB + 65536 + ((tau)&1) * 32768 + (nh)*16384;              \
    _Pragma("unroll") for (int i = 0; i < 2; ++i)                             \
        __builtin_amdgcn_global_load_lds(                                     \
            (const __attribute__((address_space(1))) void*)(Bp +              \
                offB[i][nh] + tc * 64),                                       \
            (__attribute__((address_space(3))) void*)(dbase +                 \
                (i * 512 + w * 64) * 16), 16, 0, 0);                          \
  } while (0)

template <int MODE>
__global__ __launch_bounds__(512, 2) void k_gemm8(
    const __bf16* __restrict__ Abase, const __bf16* __restrict__ Bbase,
    void* __restrict__ Cout, const float* __restrict__ aux,
    int lda, int ldb, int N, int K) {
  __shared__ __align__(128) __bf16 lds[65536];  // 128 KiB
  char* ldsB = (char*)lds;
  int tid = threadIdx.x;
  int w = tid >> 6, lane = tid & 63;
  int r16 = lane & 15, g = lane >> 4;
  int wm = w >> 2, wn = w & 3;
  int z = blockIdx.z;

  int bx, by;
  if (MODE <= 1) {  // XCD-bijective swizzle (nwg % 8 == 0 by grid choice)
    int nwg = gridDim.x * gridDim.y;
    int orig = blockIdx.y * gridDim.x + blockIdx.x;
    int cpx = nwg >> 3;
    int swz = (orig & 7) * cpx + (orig >> 3);
    bx = swz % gridDim.x; by = swz / gridDim.x;
  } else {
    bx = blockIdx.x; by = blockIdx.y;
  }
  int m0 = by * 256, n0 = bx * 256;

  const __bf16 *Ap, *Bp;
  if (MODE == 2) {
    int b = z >> 3, h = z & 7;
    Ap = Abase + (size_t)b * 1024 * 12288 + h * 512;          // Q rows
    Bp = Abase + (size_t)b * 1024 * 12288 + 4096 + h * 512;   // K rows
  } else if (MODE == 3) {
    Ap = Abase + (size_t)z * 1048576;   // P[z]
    Bp = Bbase + (size_t)z * 524288;    // Vt[z]
  } else {
    Ap = Abase; Bp = Bbase;
  }
  Ap += (size_t)m0 * lda;
  Bp += (size_t)n0 * ldb;

  // per-thread staging offsets (elements): chunk c = i*512+tid; r=c>>3, slot=c&7
  int offA[2][2], offB[2][2];
#pragma unroll
  for (int i = 0; i < 2; ++i) {
    int c = i * 512 + tid;
    int r = c >> 3, slot = c & 7;
    int colsw = (slot ^ (r & 7)) << 3;
#pragma unroll
    for (int h = 0; h < 2; ++h) {
      int RA = (r >> 6) * 128 + h * 64 + (r & 63);
      int RB = (r >> 5) * 64 + h * 32 + (r & 31);
      offA[i][h] = RA * lda + colsw;
      offB[i][h] = RB * ldb + colsw;
    }
  }

  int NT = K >> 6, NI = K >> 7;
  f32x4 acc[8][4];
#pragma unroll
  for (int a = 0; a < 8; ++a)
#pragma unroll
    for (int bq = 0; bq < 4; ++bq) acc[a][bq] = f32x4{0.f, 0.f, 0.f, 0.f};
  bf16x8 af[4][2], bq0[2][2], bq1[2][2];

  // prologue: tile0 all 4 half-tiles + tile1 first 3 -> 14 loads in flight
  STAGE_A(0, 0); STAGE_B(1, 0); STAGE_A(1, 0); STAGE_B(0, 0);
  STAGE_A(0, 1); STAGE_B(1, 1); STAGE_A(1, 1);
  VMC6();      // oldest 8 = tile0 complete
  BARRIER();

  for (int it = 0; it < NI; ++it) {
    int t0 = 2 * it;
    // p1: Q(m0,n0) of tile t0 (buf0); stage B-h0 of t0+1 (buf1)
    LDA(0, 0); LDB(0, 0, bq0);
    STAGE_B(0, t0 + 1);
    BARRIER(); WAITDS(); QUAD(0, 0, bq0); BARRIER();
    // p2: Q(m0,n1); stage A-h0 of t0+2 (buf0)
    LDB(0, 1, bq1);
    STAGE_A(0, t0 + 2);
    BARRIER(); WAITDS(); QUAD(0, 1, bq1); BARRIER();
    // p3: Q(m1,n1); stage B-h1 of t0+2
    LDA(0, 1);
    STAGE_B(1, t0 + 2);
    BARRIER(); WAITDS(); QUAD(1, 1, bq1); BARRIER();
    // p4: Q(m1,n0); stage A-h1 of t0+2; wait tile t0+1 landed
    LDB(0, 0, bq0);
    STAGE_A(1, t0 + 2);
    VMC6();
    BARRIER(); WAITDS(); QUAD(1, 0, bq0); BARRIER();
    // p5: tile t0+1 (buf1) Q(m0,n0); stage B-h0 of t0+2
    LDA(1, 0); LDB(1, 0, bq0);
    STAGE_B(0, t0 + 2);
    BARRIER(); WAITDS(); QUAD(0, 0, bq0); BARRIER();
    // p6: Q(m0,n1); stage A-h0 of t0+3 (buf1)
    LDB(1, 1, bq1);
    STAGE_A(0, t0 + 3);
    BARRIER(); WAITDS(); QUAD(0, 1, bq1); BARRIER();
    // p7: Q(m1,n1); stage B-h1 of t0+3
    LDA(1, 1);
    STAGE_B(1, t0 + 3);
    BARRIER(); WAITDS(); QUAD(1, 1, bq1); BARRIER();
    // p8: Q(m1,n0); stage A-h1 of t0+3; wait tile t0+2 landed
    LDB(1, 0, bq0);
    STAGE_A(1, t0 + 3);
    VMC6();
    BARRIER(); WAITDS(); QUAD(1, 0, bq0); BARRIER();
  }

  // epilogue: C/D layout row=(lane>>4)*4+i, col=lane&15
#pragma unroll
  for (int mig = 0; mig < 8; ++mig) {
#pragma unroll
    for (int ii = 0; ii < 4; ++ii) {
      int row = m0 + wm * 128 + mig * 16 + g * 4 + ii;
      float lval = 0.f;
      if (MODE == 3) lval = aux[z * 1024 + (row - m0) + m0];  // L[z][row]
#pragma unroll
      for (int nig = 0; nig < 4; ++nig) {
        int col = n0 + wn * 64 + nig * 16 + r16;
        float v = acc[mig][nig][ii];
        if (MODE == 0) {
          ((__bf16*)Cout)[(size_t)row * N + col] = (__bf16)v;
        } else if (MODE == 1) {
          ((float*)Cout)[(size_t)row * N + col] = v + aux[col];
        } else if (MODE == 2) {
          ((__bf16*)Cout)[(size_t)z * 1048576 + (size_t)row * 1024 + col] =
              (__bf16)__expf(v * 0.015625f);
        } else {
          ((__bf16*)Cout)[(size_t)((z >> 3) * 1024 + row) * 4096 +
                          (z & 7) * 512 + col] = (__bf16)(v / lval);
        }
      }
    }
  }
}

// ---------------------------------------------------------------------------
// Row sums of P
// ---------------------------------------------------------------------------
__global__ __launch_bounds__(256) void k_lsum(const __bf16* __restrict__ P,
                                              float* __restrict__ L) {
  int row = blockIdx.x * 4 + (threadIdx.x >> 6);
  int lane = threadIdx.x & 63;
  const __bf16* pr = P + (size_t)row * 1024;
  float s = 0.f;
#pragma unroll
  for (int j = 0; j < 2; ++j) {
    bf16x8 v = *(const bf16x8*)(pr + (j * 64 + lane) * 8);
#pragma unroll
    for (int e = 0; e < 8; ++e) s += (float)v[e];
  }
#pragma unroll
  for (int off = 32; off; off >>= 1) s += __shfl_down(s, off, 64);
  if (lane == 0) L[row] = s;
}

// ---------------------------------------------------------------------------
// Orchestration. ws layout (268.4 MB):
//   [0,        33.5MB)  xb  (x bf16)  -> reused as attnO
//   [33.5MB,  134.2MB)  wT (WqkvT)    -> reused as P(64MB)+L, then WoutT
//   [134.2MB, 234.9MB)  qkv
//   [234.9MB, 268.4MB)  vt
// ---------------------------------------------------------------------------
extern "C" void kernel_launch(void* const* d_in, const int* in_sizes, int n_in,
                              void* d_out, int out_size, void* d_ws, size_t ws_size,
                              hipStream_t stream) {
  const float* x = (const float*)d_in[0];
  const float* Wqkv = (const float*)d_in[1];
  const float* Wout = (const float*)d_in[2];
  const float* bout = (const float*)d_in[3];
  float* out = (float*)d_out;
  char* ws = (char*)d_ws;

  __bf16* xb = (__bf16*)(ws);
  __bf16* wT = (__bf16*)(ws + 33554432);
  __bf16* P = (__bf16*)(ws + 33554432);
  float* L = (float*)(ws + 33554432 + 67108864);
  __bf16* qkv = (__bf16*)(ws + 134217728);
  __bf16* vt = (__bf16*)(ws + 234881024);

  k_conv<<<16384, 256, 0, stream>>>(x, xb, 4194304);
  k_transpose_f32_bf16<<<dim3(192, 64), 256, 0, stream>>>(Wqkv, wT, 4096, 12288);
  // qkv = xb @ Wqkv : M=4096 N=12288 K=4096 -> 16x48 = 768 blocks
  k_gemm8<0><<<dim3(48, 16), 512, 0, stream>>>(xb, wT, qkv, nullptr, 4096, 4096, 12288, 4096);
  k_transpose_v<<<dim3(8, 16, 32), 256, 0, stream>>>(qkv, vt);
  // P = exp(scale * Q K^T) : per pair M=N=1024 K=512 -> 4x4x32 = 512 blocks
  k_gemm8<2><<<dim3(4, 4, 32), 512, 0, stream>>>(qkv, qkv, P, nullptr, 12288, 12288, 1024, 512);
  k_lsum<<<8192, 256, 0, stream>>>(P, L);
  // attnO = (P @ V) / L : per pair M=1024 N=512 K=1024 -> 2x4x32 = 256 blocks
  k_gemm8<3><<<dim3(2, 4, 32), 512, 0, stream>>>(P, vt, xb, L, 1024, 1024, 512, 1024);
  k_transpose_f32_bf16<<<dim3(64, 64), 256, 0, stream>>>(Wout, wT, 4096, 4096);
  // out = attnO @ Wout + bout : M=N=4096 K=4096 -> 16x16 = 256 blocks
  k_gemm8<1><<<dim3(16, 16), 512, 0, stream>>>(xb, wT, out, bout, 4096, 4096, 4096, 4096);
}

// Round 4
// 652.867 us; speedup vs baseline: 2.1997x; 1.0325x over previous
//
#include <hip/hip_runtime.h>
#include <hip/hip_bf16.h>

typedef __attribute__((ext_vector_type(8))) __bf16 bf16x8;
typedef __attribute__((ext_vector_type(4))) __bf16 bf16x4;
typedef __attribute__((ext_vector_type(4))) float f32x4;

#define MFMA16(a, b, c) __builtin_amdgcn_mfma_f32_16x16x32_bf16((a), (b), (c), 0, 0, 0)

// ---------------------------------------------------------------------------
// fp32 -> bf16 elementwise convert
// ---------------------------------------------------------------------------
__global__ __launch_bounds__(256) void k_conv(const float* __restrict__ src,
                                              __bf16* __restrict__ dst, long n4) {
  long i = (long)blockIdx.x * 256 + threadIdx.x;
  if (i >= n4) return;
  float4 v = ((const float4*)src)[i];
  bf16x4 o;
  o[0] = (__bf16)v.x; o[1] = (__bf16)v.y; o[2] = (__bf16)v.z; o[3] = (__bf16)v.w;
  ((bf16x4*)dst)[i] = o;
}

// ---------------------------------------------------------------------------
// fp32 [R][C] -> bf16 [C][R] transpose-convert
// ---------------------------------------------------------------------------
__global__ __launch_bounds__(256) void k_transpose_f32_bf16(
    const float* __restrict__ src, __bf16* __restrict__ dst, int R, int C) {
  __shared__ float tl[64][68];
  int tid = threadIdx.x;
  int r0 = blockIdx.y * 64, c0 = blockIdx.x * 64;
#pragma unroll
  for (int j = 0; j < 4; ++j) {
    int idx = j * 256 + tid;
    int row = idx >> 4, q4 = (idx & 15) * 4;
    float4 v = *(const float4*)(src + (size_t)(r0 + row) * C + c0 + q4);
    tl[row][q4 + 0] = v.x; tl[row][q4 + 1] = v.y;
    tl[row][q4 + 2] = v.z; tl[row][q4 + 3] = v.w;
  }
  __syncthreads();
#pragma unroll
  for (int j = 0; j < 2; ++j) {
    int idx = j * 256 + tid;
    int orow = idx >> 3, ch = (idx & 7) * 8;
    bf16x8 pk;
#pragma unroll
    for (int e = 0; e < 8; ++e) pk[e] = (__bf16)tl[ch + e][orow];
    *(bf16x8*)(dst + (size_t)(c0 + orow) * R + r0 + ch) = pk;
  }
}

// ---------------------------------------------------------------------------
// V slice of qkv -> Vt[pair][d][s]
// ---------------------------------------------------------------------------
__global__ __launch_bounds__(256) void k_transpose_v(
    const __bf16* __restrict__ qkv, __bf16* __restrict__ vt) {
  __shared__ __bf16 tl[64][72];
  int tid = threadIdx.x;
  int p = blockIdx.z, b = p >> 3, h = p & 7;
  int d0 = blockIdx.x * 64, s0 = blockIdx.y * 64;
  const __bf16* src = qkv + (size_t)b * 1024 * 12288 + 8192 + h * 512;
#pragma unroll
  for (int j = 0; j < 2; ++j) {
    int idx = j * 256 + tid;
    int row = idx >> 3, ch = (idx & 7) * 8;
    bf16x8 v = *(const bf16x8*)(src + (size_t)(s0 + row) * 12288 + d0 + ch);
#pragma unroll
    for (int e = 0; e < 8; ++e) tl[row][ch + e] = v[e];
  }
  __syncthreads();
#pragma unroll
  for (int j = 0; j < 2; ++j) {
    int idx = j * 256 + tid;
    int orow = idx >> 3, ch = (idx & 7) * 8;
    bf16x8 pk;
#pragma unroll
    for (int e = 0; e < 8; ++e) pk[e] = tl[ch + e][orow];
    *(bf16x8*)(vt + (size_t)p * 524288 + (size_t)(d0 + orow) * 1024 + s0 + ch) = pk;
  }
}

// ---------------------------------------------------------------------------
// 256x256 8-phase GEMM (HK-style schedule, plain HIP).
// C[M][N] = A[M][K] * Bt[N][K]^T, bf16 in, fp32 accum.
// 512 threads = 8 waves (2M x 4N); per-wave 128x64 output (acc[8][4] f32x4).
// Column-major XCD chunking for MODE<=1: XCD owns gx/8 bx-columns, by fastest
// -> B-panels L2-resident per XCD, A streams L3-aligned across XCDs.
// MODE: 0 = bf16 out; 1 = fp32 out + bias; 2 = bf16 exp(acc/64)->P + Lpart;
//       3 = bf16 acc/sum(Lpart) -> attnO scatter.
// ---------------------------------------------------------------------------
#define BARRIER() __builtin_amdgcn_s_barrier()
#define VMC6() asm volatile("s_waitcnt vmcnt(6)" ::: "memory")
#define WAITDS()                                     \
  do {                                               \
    asm volatile("s_waitcnt lgkmcnt(0)" ::: "memory"); \
    __builtin_amdgcn_sched_barrier(0);               \
  } while (0)

#define LDA(buf, mh)                                                          \
  do {                                                                        \
    _Pragma("unroll") for (int mi = 0; mi < 4; ++mi) {                        \
      int r = wm * 64 + mi * 16 + r16;                                        \
      _Pragma("unroll") for (int ks = 0; ks < 2; ++ks) {                      \
        int gg = ks * 4 + g;                                                  \
        af[mi][ks] = *(const bf16x8*)(ldsB + (buf)*32768 + (mh)*16384 +       \
                                      r * 128 + ((gg ^ (r & 7)) << 4));       \
      }                                                                       \
    }                                                                         \
  } while (0)

#define LDB(buf, nh, BQ)                                                      \
  do {                                                                        \
    _Pragma("unroll") for (int ni = 0; ni < 2; ++ni) {                        \
      int r = wn * 32 + ni * 16 + r16;                                        \
      _Pragma("unroll") for (int ks = 0; ks < 2; ++ks) {                      \
        int gg = ks * 4 + g;                                                  \
        BQ[ni][ks] = *(const bf16x8*)(ldsB + 65536 + (buf)*32768 +            \
                                      (nh)*16384 + r * 128 +                  \
                                      ((gg ^ (r & 7)) << 4));                 \
      }                                                                       \
    }                                                                         \
  } while (0)

#define QUAD(mh, nh, BQ)                                                      \
  do {                                                                        \
    __builtin_amdgcn_s_setprio(1);                                            \
    _Pragma("unroll") for (int ks = 0; ks < 2; ++ks)                          \
        _Pragma("unroll") for (int mi = 0; mi < 4; ++mi)                      \
            _Pragma("unroll") for (int ni = 0; ni < 2; ++ni)                  \
                acc[(mh)*4 + mi][(nh)*2 + ni] =                               \
                    MFMA16(af[mi][ks], BQ[ni][ks],                            \
                           acc[(mh)*4 + mi][(nh)*2 + ni]);                    \
    __builtin_amdgcn_s_setprio(0);                                            \
    __builtin_amdgcn_sched_barrier(0);                                        \
  } while (0)

#define STAGE_A(mh, tau)                                                      \
  do {                                                                        \
    int tc = (tau) < NT ? (tau) : NT - 1;                                     \
    char* dbase = ldsB + ((tau)&1) * 32768 + (mh)*16384;                      \
    _Pragma("unroll") for (int i = 0; i < 2; ++i)                             \
        __builtin_amdgcn_global_load_lds(                                     \
            (const __attribute__((address_space(1))) void*)(Ap +              \
                offA[i][mh] + tc * 64),                                       \
            (__attribute__((address_space(3))) void*)(dbase +                 \
                (i * 512 + w * 64) * 16), 16, 0, 0);                          \
  } while (0)

#define STAGE_B(nh, tau)                                                      \
  do {                                                                        \
    int tc = (tau) < NT ? (tau) : NT - 1;                                     \
    char* dbase = ldsB + 65536 + ((tau)&1) * 32768 + (nh)*16384;              \
    _Pragma("unroll") for (int i = 0; i < 2; ++i)                             \
        __builtin_amdgcn_global_load_lds(                                     \
            (const __attribute__((address_space(1))) void*)(Bp +              \
                offB[i][nh] + tc * 64),                                       \
            (__attribute__((address_space(3))) void*)(dbase +                 \
                (i * 512 + w * 64) * 16), 16, 0, 0);                          \
  } while (0)

template <int MODE>
__global__ __launch_bounds__(512, 2) void k_gemm8(
    const __bf16* __restrict__ Abase, const __bf16* __restrict__ Bbase,
    void* __restrict__ Cout, const float* __restrict__ aux,
    int lda, int ldb, int N, int K) {
  __shared__ __align__(128) __bf16 lds[65536];  // 128 KiB
  char* ldsB = (char*)lds;
  int tid = threadIdx.x;
  int w = tid >> 6, lane = tid & 63;
  int r16 = lane & 15, g = lane >> 4;
  int wm = w >> 2, wn = w & 3;
  int z = blockIdx.z;

  int bx, by;
  if (MODE <= 1) {
    // column-major XCD chunking: xcd = orig%8 owns bx in [xcd*gx/8, ...+gx/8),
    // iterating by fastest. Requires gx%8==0.
    int gx = gridDim.x, gy = gridDim.y;
    int orig = blockIdx.y * gx + blockIdx.x;
    int xcd = orig & 7, q = orig >> 3;
    int qd = q / gy;
    bx = xcd * (gx >> 3) + qd;
    by = q - qd * gy;
  } else {
    bx = blockIdx.x; by = blockIdx.y;
  }
  int m0 = by * 256, n0 = bx * 256;

  const __bf16 *Ap, *Bp;
  if (MODE == 2) {
    int b = z >> 3, h = z & 7;
    Ap = Abase + (size_t)b * 1024 * 12288 + h * 512;          // Q rows
    Bp = Abase + (size_t)b * 1024 * 12288 + 4096 + h * 512;   // K rows
  } else if (MODE == 3) {
    Ap = Abase + (size_t)z * 1048576;   // P[z]
    Bp = Bbase + (size_t)z * 524288;    // Vt[z]
  } else {
    Ap = Abase; Bp = Bbase;
  }
  Ap += (size_t)m0 * lda;
  Bp += (size_t)n0 * ldb;

  int offA[2][2], offB[2][2];
#pragma unroll
  for (int i = 0; i < 2; ++i) {
    int c = i * 512 + tid;
    int r = c >> 3, slot = c & 7;
    int colsw = (slot ^ (r & 7)) << 3;
#pragma unroll
    for (int h = 0; h < 2; ++h) {
      int RA = (r >> 6) * 128 + h * 64 + (r & 63);
      int RB = (r >> 5) * 64 + h * 32 + (r & 31);
      offA[i][h] = RA * lda + colsw;
      offB[i][h] = RB * ldb + colsw;
    }
  }

  int NT = K >> 6, NI = K >> 7;
  f32x4 acc[8][4];
#pragma unroll
  for (int a = 0; a < 8; ++a)
#pragma unroll
    for (int bq = 0; bq < 4; ++bq) acc[a][bq] = f32x4{0.f, 0.f, 0.f, 0.f};
  bf16x8 af[4][2], bq0[2][2], bq1[2][2];

  // prologue: tile0 all 4 half-tiles + tile1 first 3 -> 14 loads in flight
  STAGE_A(0, 0); STAGE_B(1, 0); STAGE_A(1, 0); STAGE_B(0, 0);
  STAGE_A(0, 1); STAGE_B(1, 1); STAGE_A(1, 1);
  VMC6();
  BARRIER();

  for (int it = 0; it < NI; ++it) {
    int t0 = 2 * it;
    // p1: Q(m0,n0) tile t0 (buf0); stage B-h0 of t0+1
    LDA(0, 0); LDB(0, 0, bq0);
    STAGE_B(0, t0 + 1);
    BARRIER(); WAITDS(); QUAD(0, 0, bq0); BARRIER();
    // p2: Q(m0,n1); stage A-h0 of t0+2
    LDB(0, 1, bq1);
    STAGE_A(0, t0 + 2);
    BARRIER(); WAITDS(); QUAD(0, 1, bq1); BARRIER();
    // p3: Q(m1,n1); stage B-h1 of t0+2
    LDA(0, 1);
    STAGE_B(1, t0 + 2);
    BARRIER(); WAITDS(); QUAD(1, 1, bq1); BARRIER();
    // p4: Q(m1,n0) (bq0 regs still valid); stage A-h1 of t0+2; wait t0+1
    STAGE_A(1, t0 + 2);
    VMC6();
    BARRIER(); WAITDS(); QUAD(1, 0, bq0); BARRIER();
    // p5: tile t0+1 (buf1) Q(m0,n0); stage B-h0 of t0+2
    LDA(1, 0); LDB(1, 0, bq0);
    STAGE_B(0, t0 + 2);
    BARRIER(); WAITDS(); QUAD(0, 0, bq0); BARRIER();
    // p6: Q(m0,n1); stage A-h0 of t0+3
    LDB(1, 1, bq1);
    STAGE_A(0, t0 + 3);
    BARRIER(); WAITDS(); QUAD(0, 1, bq1); BARRIER();
    // p7: Q(m1,n1); stage B-h1 of t0+3
    LDA(1, 1);
    STAGE_B(1, t0 + 3);
    BARRIER(); WAITDS(); QUAD(1, 1, bq1); BARRIER();
    // p8: Q(m1,n0) (bq0 regs valid); stage A-h1 of t0+3; wait t0+2
    STAGE_A(1, t0 + 3);
    VMC6();
    BARRIER(); WAITDS(); QUAD(1, 0, bq0); BARRIER();
  }

  if (MODE == 2) {
    // drain staging DMA before reusing LDS as row-sum scratch
    asm volatile("s_waitcnt vmcnt(0)" ::: "memory");
    __syncthreads();
    float* Lbuf = (float*)ldsB;  // [wm][wn][128] = 4 KB
#pragma unroll
    for (int mig = 0; mig < 8; ++mig) {
#pragma unroll
      for (int ii = 0; ii < 4; ++ii) {
        int row = m0 + wm * 128 + mig * 16 + g * 4 + ii;
        float s = 0.f;
#pragma unroll
        for (int nig = 0; nig < 4; ++nig) {
          int col = n0 + wn * 64 + nig * 16 + r16;
          float e = __expf(acc[mig][nig][ii] * 0.015625f);
          ((__bf16*)Cout)[(size_t)z * 1048576 + (size_t)row * 1024 + col] =
              (__bf16)e;
          s += e;
        }
        s += __shfl_xor(s, 1, 64);
        s += __shfl_xor(s, 2, 64);
        s += __shfl_xor(s, 4, 64);
        s += __shfl_xor(s, 8, 64);
        if (r16 == 0)
          Lbuf[(wm * 4 + wn) * 128 + mig * 16 + g * 4 + ii] = s;
      }
    }
    __syncthreads();
    if (tid < 256) {
      int wmi = tid >> 7, rl = tid & 127;
      const float* base = Lbuf + wmi * 512;
      float s = base[rl] + base[128 + rl] + base[256 + rl] + base[384 + rl];
      ((float*)aux)[z * 4096 + blockIdx.x * 1024 + m0 + tid] = s;
    }
    return;
  }

#pragma unroll
  for (int mig = 0; mig < 8; ++mig) {
#pragma unroll
    for (int ii = 0; ii < 4; ++ii) {
      int row = m0 + wm * 128 + mig * 16 + g * 4 + ii;
      float lval = 0.f;
      if (MODE == 3)
        lval = aux[z * 4096 + row] + aux[z * 4096 + 1024 + row] +
               aux[z * 4096 + 2048 + row] + aux[z * 4096 + 3072 + row];
#pragma unroll
      for (int nig = 0; nig < 4; ++nig) {
        int col = n0 + wn * 64 + nig * 16 + r16;
        float v = acc[mig][nig][ii];
        if (MODE == 0) {
          ((__bf16*)Cout)[(size_t)row * N + col] = (__bf16)v;
        } else if (MODE == 1) {
          ((float*)Cout)[(size_t)row * N + col] = v + aux[col];
        } else if (MODE == 3) {
          ((__bf16*)Cout)[(size_t)((z >> 3) * 1024 + row) * 4096 +
                          (z & 7) * 512 + col] = (__bf16)(v / lval);
        }
      }
    }
  }
}

// ---------------------------------------------------------------------------
// Orchestration. ws layout (268.4 MB):
//   [0,        33.5MB)  xb  (x bf16)  -> reused as attnO
//   [33.5MB,  134.2MB)  wT (WqkvT)    -> reused as P(64MB)+Lpart, then WoutT
//   [134.2MB, 234.9MB)  qkv
//   [234.9MB, 268.4MB)  vt
// ---------------------------------------------------------------------------
extern "C" void kernel_launch(void* const* d_in, const int* in_sizes, int n_in,
                              void* d_out, int out_size, void* d_ws, size_t ws_size,
                              hipStream_t stream) {
  const float* x = (const float*)d_in[0];
  const float* Wqkv = (const float*)d_in[1];
  const float* Wout = (const float*)d_in[2];
  const float* bout = (const float*)d_in[3];
  float* out = (float*)d_out;
  char* ws = (char*)d_ws;

  __bf16* xb = (__bf16*)(ws);
  __bf16* wT = (__bf16*)(ws + 33554432);
  __bf16* P = (__bf16*)(ws + 33554432);
  float* Lpart = (float*)(ws + 33554432 + 67108864);  // [32][4][1024] = 512 KB
  __bf16* qkv = (__bf16*)(ws + 134217728);
  __bf16* vt = (__bf16*)(ws + 234881024);

  k_conv<<<16384, 256, 0, stream>>>(x, xb, 4194304);
  k_transpose_f32_bf16<<<dim3(192, 64), 256, 0, stream>>>(Wqkv, wT, 4096, 12288);
  // qkv = xb @ Wqkv : M=4096 N=12288 K=4096 -> 48x16 = 768 blocks
  k_gemm8<0><<<dim3(48, 16), 512, 0, stream>>>(xb, wT, qkv, nullptr, 4096, 4096, 12288, 4096);
  k_transpose_v<<<dim3(8, 16, 32), 256, 0, stream>>>(qkv, vt);
  // P = exp(scale * Q K^T) + Lpart : per pair M=N=1024 K=512
  k_gemm8<2><<<dim3(4, 4, 32), 512, 0, stream>>>(qkv, qkv, P, Lpart, 12288, 12288, 1024, 512);
  // attnO = (P @ V) / L : per pair M=1024 N=512 K=1024
  k_gemm8<3><<<dim3(2, 4, 32), 512, 0, stream>>>(P, vt, xb, Lpart, 1024, 1024, 512, 1024);
  k_transpose_f32_bf16<<<dim3(64, 64), 256, 0, stream>>>(Wout, wT, 4096, 4096);
  // out = attnO @ Wout + bout : M=N=4096 K=4096 -> 16x16 = 256 blocks
  k_gemm8<1><<<dim3(16, 16), 512, 0, stream>>>(xb, wT, out, bout, 4096, 4096, 4096, 4096);
}